// Round 7
// baseline (100.695 us; speedup 1.0000x reference)
//
#include <hip/hip_runtime.h>
#include <math.h>

#define LL 768
#define CT 64
#define KD 192
#define OC 1024
#define NIS 48    // 48 i-strips of 16 rows -> col-partial strips

// ---------------- K_A: one block per row ----------------
// Streams row i sequentially (196KB). Computes e[i,j] = exp(logit_ij + bq),
// z_row, and row_feat[i,:] = sum_j e*f / z -- complete, no partials.
// thread: u = t>>4 (pair slot), q = t&15 (channel quad).
__global__ __launch_bounds__(256) void k_rows(const float* __restrict__ feat,
                                              const float* __restrict__ Wq,
                                              const float* __restrict__ bq,
                                              float* __restrict__ e_buf,
                                              float* __restrict__ rfeat) {
    __shared__ float rfold[16][68];
    __shared__ float zfold[4];
    int t = threadIdx.x, u = t >> 4, q = t & 15, w = t >> 6;
    int row = blockIdx.x;

    const float4 wq = *reinterpret_cast<const float4*>(Wq + q * 4);
    const float bqv = bq[0];
    const float* fb = feat + ((size_t)row * LL + u) * CT + q * 4;
    float* eb = e_buf + (size_t)row * LL + u;

    float4 racc = make_float4(0.f, 0.f, 0.f, 0.f);
    float zacc = 0.f;
    #pragma unroll 4
    for (int jb = 0; jb < 48; ++jb) {
        const float4 f = *reinterpret_cast<const float4*>(fb + jb * 16 * CT);
        float s = f.x * wq.x + f.y * wq.y + f.z * wq.z + f.w * wq.w;
        s += __shfl_xor(s, 1);
        s += __shfl_xor(s, 2);
        s += __shfl_xor(s, 4);
        s += __shfl_xor(s, 8);
        float e = __expf(s + bqv);
        racc.x = fmaf(e, f.x, racc.x);
        racc.y = fmaf(e, f.y, racc.y);
        racc.z = fmaf(e, f.z, racc.z);
        racc.w = fmaf(e, f.w, racc.w);
        zacc += e;
        if (q == 0) eb[jb * 16] = e;
    }
    // z: sum over the wave's 4 u-slots (q-duplicated, so xor16/32 gives wave z)
    zacc += __shfl_xor(zacc, 16);
    zacc += __shfl_xor(zacc, 32);
    if ((t & 63) == 0) zfold[w] = zacc;
    *reinterpret_cast<float4*>(&rfold[u][q * 4]) = racc;
    __syncthreads();
    if (t < 64) {
        float z = zfold[0] + zfold[1] + zfold[2] + zfold[3];
        float inv = 1.0f / z;
        float sum = 0.f;
        #pragma unroll
        for (int uu = 0; uu < 16; ++uu) sum += rfold[uu][t];
        rfeat[(size_t)row * CT + t] = sum * inv;
    }
}

// ---------------- K_B: chain-free col partials ----------------
// tile = 16 rows x 48 cols. blockIdx.x = j-strip (16), .y = i-strip (48).
// thread: u = t>>4 -> col within 16-col group, q = t&15 -> channel quad.
// Per i: 3x 1KB/wave loads + 3 scalar e loads + 12 fma. No shfl/exp/LDS.
// cp[s][j][c] = sum_{i in strip s} e[i,j] f[i,j,c]; cz[s][j] = sum e.
__global__ __launch_bounds__(256) void k_cols(const float* __restrict__ feat,
                                              const float* __restrict__ e_buf,
                                              float* __restrict__ cp,
                                              float* __restrict__ cz) {
    int t = threadIdx.x, u = t >> 4, q = t & 15;
    int j0 = blockIdx.x * 48, i0 = blockIdx.y * 16;

    const float* fb = feat + ((size_t)i0 * LL + j0 + u) * CT + q * 4;
    const float* ebase = e_buf + (size_t)i0 * LL + j0 + u;

    float4 c0 = make_float4(0.f, 0.f, 0.f, 0.f);
    float4 c1 = make_float4(0.f, 0.f, 0.f, 0.f);
    float4 c2 = make_float4(0.f, 0.f, 0.f, 0.f);
    float z0 = 0.f, z1 = 0.f, z2 = 0.f;

    #pragma unroll 2
    for (int ii = 0; ii < 16; ++ii) {
        const float* fr = fb + (size_t)ii * LL * CT;
        const float* er = ebase + (size_t)ii * LL;
        float e0 = er[0], e1 = er[16], e2 = er[32];
        const float4 f0 = *reinterpret_cast<const float4*>(fr + 0 * 16 * CT);
        const float4 f1 = *reinterpret_cast<const float4*>(fr + 1 * 16 * CT);
        const float4 f2 = *reinterpret_cast<const float4*>(fr + 2 * 16 * CT);
        c0.x = fmaf(e0, f0.x, c0.x); c0.y = fmaf(e0, f0.y, c0.y);
        c0.z = fmaf(e0, f0.z, c0.z); c0.w = fmaf(e0, f0.w, c0.w);
        c1.x = fmaf(e1, f1.x, c1.x); c1.y = fmaf(e1, f1.y, c1.y);
        c1.z = fmaf(e1, f1.z, c1.z); c1.w = fmaf(e1, f1.w, c1.w);
        c2.x = fmaf(e2, f2.x, c2.x); c2.y = fmaf(e2, f2.y, c2.y);
        c2.z = fmaf(e2, f2.z, c2.z); c2.w = fmaf(e2, f2.w, c2.w);
        z0 += e0; z1 += e1; z2 += e2;
    }

    size_t base = ((size_t)blockIdx.y * LL + j0 + u) * CT + q * 4;
    *reinterpret_cast<float4*>(cp + base + 0 * 16 * CT) = c0;
    *reinterpret_cast<float4*>(cp + base + 1 * 16 * CT) = c1;
    *reinterpret_cast<float4*>(cp + base + 2 * 16 * CT) = c2;
    if (q == 0) {
        size_t zb = (size_t)blockIdx.y * LL + j0 + u;
        cz[zb + 0 * 16] = z0;
        cz[zb + 1 * 16] = z1;
        cz[zb + 2 * 16] = z2;
    }
}

// ---------------- K_C: col-combine (own 8 lines) + diag + LN + GEMM ----------
__global__ __launch_bounds__(256) void k_final(const float* __restrict__ feat,
                                               const float* __restrict__ rfeat,
                                               const float* __restrict__ cp,
                                               const float* __restrict__ cz,
                                               const float* __restrict__ ln_g,
                                               const float* __restrict__ ln_b,
                                               const float* __restrict__ WU,
                                               const float* __restrict__ bU,
                                               const float* __restrict__ WV,
                                               const float* __restrict__ bV,
                                               const float* __restrict__ sigma,
                                               float* __restrict__ out) {
    __shared__ float cf[8][66];
    __shared__ float zcl[8];
    __shared__ float xbuf[8][KD];
    int t = threadIdx.x;
    int r0 = blockIdx.x * 8;
    int right = blockIdx.y;

    // combine cfeat for lines r0..r0+7 (j-index = output row index)
    {
        int r = t >> 5, cpair = t & 31;
        const float* p = cp + ((size_t)0 * LL + r0 + r) * CT + cpair * 2;
        float a0 = 0.f, a1 = 0.f;
        #pragma unroll 4
        for (int s = 0; s < NIS; ++s) {
            const float2 v = *reinterpret_cast<const float2*>(p + (size_t)s * LL * CT);
            a0 += v.x; a1 += v.y;
        }
        if (t < 8) {
            float z = 0.f;
            #pragma unroll 4
            for (int s = 0; s < NIS; ++s) z += cz[(size_t)s * LL + r0 + t];
            zcl[t] = 1.0f / z;
        }
        __syncthreads();
        float inv = zcl[r];
        cf[r][cpair * 2] = a0 * inv;
        cf[r][cpair * 2 + 1] = a1 * inv;
    }
    __syncthreads();

    int wid = t >> 6, l = t & 63;
    for (int r = wid; r < 8; r += 4) {
        int i = r0 + r;
        float d  = feat[((size_t)i * LL + i) * CT + l];
        float rv = rfeat[(size_t)i * CT + l];
        float cv = cf[r][l];
        float sum = d + rv + cv;
        #pragma unroll
        for (int o = 32; o; o >>= 1) sum += __shfl_xor(sum, o);
        float mu = sum * (1.0f / 192.0f);
        float d0 = d - mu, d1 = rv - mu, d2 = cv - mu;
        float sq = d0 * d0 + d1 * d1 + d2 * d2;
        #pragma unroll
        for (int o = 32; o; o >>= 1) sq += __shfl_xor(sq, o);
        float rstd = rsqrtf(sq * (1.0f / 192.0f) + 1e-5f);
        float h0 = d0 * rstd, h1 = d1 * rstd, h2 = d2 * rstd;
        float a1 = right ? h2 : h1;
        float a2 = right ? h1 : h2;
        xbuf[r][l]       = h0 * ln_g[l]       + ln_b[l];
        xbuf[r][64 + l]  = a1 * ln_g[64 + l]  + ln_b[64 + l];
        xbuf[r][128 + l] = a2 * ln_g[128 + l] + ln_b[128 + l];
    }
    __syncthreads();

    const float* W    = right ? WV : WU;
    const float* bias = right ? bV : bU;
    int o = t * 4;
    float4 acc[8];
    #pragma unroll
    for (int r = 0; r < 8; ++r) acc[r] = make_float4(0.f, 0.f, 0.f, 0.f);

    for (int k = 0; k < KD; k += 4) {
        float4 xr[8];
        #pragma unroll
        for (int r = 0; r < 8; ++r)
            xr[r] = *reinterpret_cast<const float4*>(&xbuf[r][k]);
        #pragma unroll
        for (int kk = 0; kk < 4; ++kk) {
            float4 w = *reinterpret_cast<const float4*>(W + (size_t)(k + kk) * OC + o);
            #pragma unroll
            for (int r = 0; r < 8; ++r) {
                float xv = (&xr[r].x)[kk];
                acc[r].x = fmaf(xv, w.x, acc[r].x);
                acc[r].y = fmaf(xv, w.y, acc[r].y);
                acc[r].z = fmaf(xv, w.z, acc[r].z);
                acc[r].w = fmaf(xv, w.w, acc[r].w);
            }
        }
    }

    float4 bb = *reinterpret_cast<const float4*>(bias + o);
    float sg = right ? 1.0f : sigma[o >> 7];
    float* obase = out + (right ? (size_t)LL * OC : 0);
    #pragma unroll
    for (int r = 0; r < 8; ++r) {
        float4 v;
        v.x = (acc[r].x + bb.x) * sg;
        v.y = (acc[r].y + bb.y) * sg;
        v.z = (acc[r].z + bb.z) * sg;
        v.w = (acc[r].w + bb.w) * sg;
        *reinterpret_cast<float4*>(obase + (size_t)(r0 + r) * OC + o) = v;
    }
}

extern "C" void kernel_launch(void* const* d_in, const int* in_sizes, int n_in,
                              void* d_out, int out_size, void* d_ws, size_t ws_size,
                              hipStream_t stream) {
    const float* feat  = (const float*)d_in[0];
    const float* Wq    = (const float*)d_in[1];
    const float* bq    = (const float*)d_in[2];
    const float* ln_g  = (const float*)d_in[3];
    const float* ln_b  = (const float*)d_in[4];
    const float* WU    = (const float*)d_in[5];
    const float* bU    = (const float*)d_in[6];
    const float* WV    = (const float*)d_in[7];
    const float* bV    = (const float*)d_in[8];
    const float* sigma = (const float*)d_in[9];
    float* out = (float*)d_out;

    float* ws    = (float*)d_ws;
    float* e_buf = ws;                                   // LL*LL
    float* rfeat = e_buf + (size_t)LL * LL;              // LL*CT
    float* cp    = rfeat + (size_t)LL * CT;              // NIS*LL*CT
    float* cz    = cp + (size_t)NIS * LL * CT;           // NIS*LL

    hipLaunchKernelGGL(k_rows, dim3(LL), dim3(256), 0, stream,
                       feat, Wq, bq, e_buf, rfeat);
    hipLaunchKernelGGL(k_cols, dim3(LL / 48, NIS), dim3(256), 0, stream,
                       feat, e_buf, cp, cz);
    hipLaunchKernelGGL(k_final, dim3(LL / 8, 2), dim3(256), 0, stream,
                       feat, rfeat, cp, cz, ln_g, ln_b, WU, bU, WV, bV, sigma, out);
}